// Round 14
// baseline (408.383 us; speedup 1.0000x reference)
//
#include <hip/hip_runtime.h>
#include <stdint.h>

// W8A8B32O32 Linear: y[m][n] = sum_k x[m][k]*w[n][k] + bias[n]
// M=8192, N=4096, K=4096. Inputs arrive as int32 (one int per logical int8
// element); pack to int8 in d_ws, then run the i8 MFMA GEMM.
#define M_TOT 8192
#define N_TOT 4096
#define K_TOT 4096

typedef int v4i  __attribute__((ext_vector_type(4)));
typedef int v16i __attribute__((ext_vector_type(16)));

__device__ __forceinline__ void gload_lds16(const void* g, void* l) {
    __builtin_amdgcn_global_load_lds(
        (const __attribute__((address_space(1))) unsigned int*)g,
        (__attribute__((address_space(3))) unsigned int*)l,
        16, 0, 0);
}

// gfx9 s_waitcnt simm16: vmcnt[3:0]@[3:0], expcnt@[6:4], lgkmcnt@[11:8],
// vmcnt[5:4]@[15:14].
#define WAIT_V4_L0() __builtin_amdgcn_s_waitcnt(0x0074)  // vmcnt(4) lgkmcnt(0)
#define WAIT_V0_L0() __builtin_amdgcn_s_waitcnt(0x0070)  // vmcnt(0) lgkmcnt(0)
#define WAIT_V6()    __builtin_amdgcn_s_waitcnt(0x0f76)  // vmcnt(6), lgkm free
#define SBAR()       __builtin_amdgcn_s_barrier()
#define SFENCE()     __builtin_amdgcn_sched_barrier(0)

// ---- fused pack int32 -> int8: 64B loads -> 16B store per thread-iter ----
// BW-bound at 240 MB (~45 us); at the traffic floor (R3-R9).
__global__ __launch_bounds__(256) void pack2(
        const int4* __restrict__ xs, int4* __restrict__ xd,
        const int4* __restrict__ ws, int4* __restrict__ wd) {
    const int t = blockIdx.x * 256 + threadIdx.x;       // 0..524287
#pragma unroll
    for (int it = 0; it < 6; ++it) {
        const long g = (long)it * 524288 + t;
        const int4* __restrict__ src = (it < 4) ? xs : ws;
        int4* __restrict__ dst       = (it < 4) ? xd : wd;
        const long o = (it < 4) ? g : g - 2097152;
        int4 r;
        int* rp = (int*)&r;
#pragma unroll
        for (int q = 0; q < 4; ++q) {
            const int4 a = src[o * 4 + q];
            rp[q] = (a.x & 255) | ((a.y & 255) << 8) |
                    ((a.z & 255) << 16) | (a.w << 24);
        }
        dst[o] = r;
    }
}

// ---- GEMM: 256 threads = 4 waves, 256x128 tile, 2 INDEPENDENT blocks/CU --
// R13 audit: R11 (the "independent contexts" test) was CONFOUNDED -- it cut
// wave-tile AI in half and blew FETCH to 352 MB at ~1.9 TB/s (plausibly
// memory-limited), so it cannot falsify decoupling. This is the clean test:
// per-wave geometry, read pattern, MFMA count, and cadence are IDENTICAL to
// R4/R13 (128x64 wave tile, 2-phase kk split, triple buffer, counted vmcnt,
// one barrier/iter); the ONLY change is that the two waves sharing a SIMD
// now come from DIFFERENT blocks (4-wave block, 72 KB LDS -> 2 blocks/CU;
// ~228 unified regs -> 2 waves/SIMD). Same-block waves stall at the same
// barrier/waitcnt TOGETHER; different-block waves cannot -- one block's
// MFMA stream covers the other's sync window.
//
// Per K-iter (per wave; tile kt in A0/B0, kt+1 in A1/B1, kt+2 -> A2/B2):
//   1) ds_read kk=1 frags of kt (6)         (hidden under step 3)
//   2) issue 4 DMAs: A-half of kt+2
//   3) MFMA kk=0 x8 (setprio)
//   4) s_waitcnt vmcnt(4) lgkmcnt(0); s_barrier
//      [queue: [A(kt+1)x4][B(kt+1)x2][A(kt+2)x4] -> vmcnt(4) drains tile
//       kt+1's 6 exactly, keeps kt+2's 4 in flight; retires my reads]
//   5) ds_read kk=0 frags of kt+1 (6)       (hidden under step 7)
//   6) issue 2 DMAs: B-half of kt+2
//   7) MFMA kk=1 x8 (setprio)
//   rotate buffers.
// Tail iters (kt+2>=NT) use vmcnt(0). Buffer-reuse proof: step-2/6 DMAs
// target the buffer of tile kt-1, whose last reads (iter kt-1 step 1) were
// retired by iter kt-1 step 4's lgkmcnt(0) in EVERY wave of this block
// before its barrier; our issue is after. Reads of kt+1 at step 5 follow
// each wave's own vmcnt drain + the same barrier. Explicit waits REQUIRED:
// compiler alias analysis does not connect global_load_lds's LDS write to
// the ds_reads. XOR chunk swizzle (R4-proven): stored_chunk =
// logical_chunk ^ ((row>>1)&3); fetch chunk fc = (lane&3)^((lane>>3)&3);
// residual 4-way read conflicts are hidden (R6 measured).
__global__ __launch_bounds__(256, 2) void i8gemm_bias(
        const signed char* __restrict__ x,
        const signed char* __restrict__ w,
        const int* __restrict__ bias,
        int* __restrict__ out) {
    __shared__ __align__(16) signed char la[3][256 * 64];   // A: 256 rows
    __shared__ __align__(16) signed char lb[3][128 * 64];   // B: 128 rows

    const int tid  = threadIdx.x;
    const int lane = tid & 63;           // 0..63
    const int wv   = tid >> 6;           // wave 0..3
    const int l31  = lane & 31;
    const int kh   = lane >> 5;          // K-half this lane supplies to MFMA
    const int wr   = wv >> 1;            // quadrant row (0..1) -> 128 rows
    const int wc   = wv & 1;             // quadrant col (0..1) -> 64 cols

    // XCD-aware bijective swizzle (1024 blocks, 1024%8==0): XCD k gets 128
    // consecutive swz = 4 M-panels x all 32 N-blocks (K-step working set
    // 4x16KB A + 256KB B << 4MB L2).
    const int flat = blockIdx.y * gridDim.x + blockIdx.x;   // 0..1023
    const int swz  = (flat & 7) * 128 + (flat >> 3);
    const int bn0  = (swz & 31) * 128;
    const int bm0  = (swz >> 5) * 256;

    // Fused bias: C/D col = lane&31 -> bias is lane-constant per fragment.
    int bv[2];
#pragma unroll
    for (int j = 0; j < 2; ++j) bv[j] = bias[bn0 + wc * 64 + j * 32 + l31];
    v16i acc[4][2];
#pragma unroll
    for (int i = 0; i < 4; ++i)
#pragma unroll
        for (int j = 0; j < 2; ++j)
#pragma unroll
            for (int r = 0; r < 16; ++r) acc[i][j][r] = bv[j];

    // Staging: wave wv covers A rows [wv*64, wv*64+64) (4 issues) and
    // B rows [wv*32, wv*32+32) (2 issues); issue i covers rows i*16+(lane>>2);
    // stored chunk = lane&3; fetch chunk fc = (lane&3)^((lane>>3)&3)
    // (wv*64, wv*32, i*16 all 0 mod 8 -> (row>>1)&3 = (lane>>3)&3).
    const int fc = (lane & 3) ^ ((lane >> 3) & 3);
    const signed char* pa = x + (long)(bm0 + wv * 64 + (lane >> 2)) * K_TOT + fc * 16;
    const signed char* pb = w + (long)(bn0 + wv * 32 + (lane >> 2)) * K_TOT + fc * 16;
    const int lba = wv * 64 * 64;        // A dst base (+ i*1024 per issue)
    const int lbb = wv * 32 * 64;        // B dst base (+ i*1024 per issue)

    // Fragment reads: A row = wr*128 + i*32 + l31, B row = wc*64 + j*32 + l31
    // -> swr = (l31>>1)&3 (bases 0 mod 8); logical chunk kk*2+kh at slot
    // (kk*2+kh)^swr.
    const int swr  = (l31 >> 1) & 3;
    const int aoff = (wr * 128 + l31) * 64;
    const int boff = (wc * 64  + l31) * 64;
    const int cs0  = ((kh    ) ^ swr) * 16;   // kk=0 chunk byte offset
    const int cs1  = ((2 + kh) ^ swr) * 16;   // kk=1 chunk byte offset

    // Rotating buffer pointers: A0/B0 = tile kt, A1/B1 = kt+1, A2/B2 = kt+2.
    signed char* A0 = &la[0][0]; signed char* A1 = &la[1][0]; signed char* A2 = &la[2][0];
    signed char* B0 = &lb[0][0]; signed char* B1 = &lb[1][0]; signed char* B2 = &lb[2][0];

    // Prologue: stage tile 0 then tile 1, grouped per tile (vmcnt decrements
    // in issue order). 6 DMAs per tile per wave (4 A + 2 B).
#pragma unroll
    for (int i = 0; i < 4; ++i)
        gload_lds16(pa + (long)i * 16 * K_TOT, A0 + lba + i * 1024);
#pragma unroll
    for (int i = 0; i < 2; ++i)
        gload_lds16(pb + (long)i * 16 * K_TOT, B0 + lbb + i * 1024);
#pragma unroll
    for (int i = 0; i < 4; ++i)
        gload_lds16(pa + 64 + (long)i * 16 * K_TOT, A1 + lba + i * 1024);
#pragma unroll
    for (int i = 0; i < 2; ++i)
        gload_lds16(pb + 64 + (long)i * 16 * K_TOT, B1 + lbb + i * 1024);
    WAIT_V6();                 // tile 0's 6 landed (tile 1's 6 in flight)
    SBAR();
    SFENCE();

    // Preload kk=0 fragments of tile 0.
    v4i a0[4], b0[2], a1[4], b1[2];
#pragma unroll
    for (int i = 0; i < 4; ++i) a0[i] = *(const v4i*)(A0 + aoff + i * 2048 + cs0);
#pragma unroll
    for (int j = 0; j < 2; ++j) b0[j] = *(const v4i*)(B0 + boff + j * 2048 + cs0);

    const int NT = K_TOT / 64;           // 64 K-tiles
    for (int kt = 0; kt < NT; ++kt) {
        SFENCE();
        // 1) ds_read kk=1 of tile kt (consumed by step 7; hidden by step 3).
#pragma unroll
        for (int i = 0; i < 4; ++i) a1[i] = *(const v4i*)(A0 + aoff + i * 2048 + cs1);
#pragma unroll
        for (int j = 0; j < 2; ++j) b1[j] = *(const v4i*)(B0 + boff + j * 2048 + cs1);
        SFENCE();
        // 2) Issue A-half prefetch of tile kt+2 (fire-and-forget).
        if (kt + 2 < NT) {
            const long k0 = (long)(kt + 2) * 64;
#pragma unroll
            for (int i = 0; i < 4; ++i)
                gload_lds16(pa + k0 + (long)i * 16 * K_TOT, A2 + lba + i * 1024);
        }
        SFENCE();
        // 3) MFMA kk=0 (8): hides step-1 reads and step-2 issues.
        __builtin_amdgcn_s_setprio(1);
#pragma unroll
        for (int i = 0; i < 4; ++i)
#pragma unroll
            for (int j = 0; j < 2; ++j)
                acc[i][j] = __builtin_amdgcn_mfma_i32_32x32x32_i8(
                    a0[i], b0[j], acc[i][j], 0, 0, 0);
        __builtin_amdgcn_s_setprio(0);
        SFENCE();
        // 4) Publish/acquire: tile kt+1 landed everywhere, my reads retired.
        if (kt + 2 < NT) { WAIT_V4_L0(); } else { WAIT_V0_L0(); }
        SFENCE();
        SBAR();
        SFENCE();
        // 5) ds_read kk=0 of tile kt+1 (hidden by step 7).
        if (kt + 1 < NT) {
#pragma unroll
            for (int i = 0; i < 4; ++i) a0[i] = *(const v4i*)(A1 + aoff + i * 2048 + cs0);
#pragma unroll
            for (int j = 0; j < 2; ++j) b0[j] = *(const v4i*)(B1 + boff + j * 2048 + cs0);
        }
        SFENCE();
        // 6) Issue B-half prefetch of tile kt+2 (fire-and-forget).
        if (kt + 2 < NT) {
            const long k0 = (long)(kt + 2) * 64;
#pragma unroll
            for (int i = 0; i < 2; ++i)
                gload_lds16(pb + k0 + (long)i * 16 * K_TOT, B2 + lbb + i * 1024);
        }
        SFENCE();
        // 7) MFMA kk=1 (8): hides step-5 reads (a1/b1 drained at step 4).
        __builtin_amdgcn_s_setprio(1);
#pragma unroll
        for (int i = 0; i < 4; ++i)
#pragma unroll
            for (int j = 0; j < 2; ++j)
                acc[i][j] = __builtin_amdgcn_mfma_i32_32x32x32_i8(
                    a1[i], b1[j], acc[i][j], 0, 0, 0);
        __builtin_amdgcn_s_setprio(0);

        // Rotate buffers (register pointer swap, no dynamic indexing).
        signed char* t;
        t = A0; A0 = A1; A1 = A2; A2 = t;
        t = B0; B0 = B1; B1 = B2; B2 = t;
    }

    // Epilogue: C/D layout col=lane&31, row=(reg&3)+8*(reg>>2)+4*(lane>>5).
#pragma unroll
    for (int i = 0; i < 4; ++i) {
        const int mbase = bm0 + wr * 128 + i * 32 + 4 * kh;
#pragma unroll
        for (int j = 0; j < 2; ++j) {
            const int n = bn0 + wc * 64 + j * 32 + l31;
#pragma unroll
            for (int r = 0; r < 16; ++r) {
                const int m = mbase + (r & 3) + 8 * (r >> 2);
                out[(long)m * N_TOT + n] = acc[i][j][r];
            }
        }
    }
}

extern "C" void kernel_launch(void* const* d_in, const int* in_sizes, int n_in,
                              void* d_out, int out_size, void* d_ws, size_t ws_size,
                              hipStream_t stream) {
    const int* x32  = (const int*)d_in[0];  // [8192,4096] logical i8 as i32
    const int* w32  = (const int*)d_in[1];  // [4096,4096] logical i8 as i32
    const int* bias = (const int*)d_in[2];  // [4096] i32
    int*       out  = (int*)d_out;          // [8192,4096] i32

    signed char* xp = (signed char*)d_ws;
    signed char* wp = (signed char*)d_ws + (size_t)M_TOT * K_TOT;

    pack2<<<2048, 256, 0, stream>>>((const int4*)x32, (int4*)xp,
                                    (const int4*)w32, (int4*)wp);

    dim3 grid(N_TOT / 128, M_TOT / 256);  // (32, 32) = 1024 blocks
    i8gemm_bias<<<grid, 256, 0, stream>>>(xp, wp, bias, out);
}

// Round 15
// 395.695 us; speedup vs baseline: 1.0321x; 1.0321x over previous
//
#include <hip/hip_runtime.h>
#include <stdint.h>

// W8A8B32O32 Linear: y[m][n] = sum_k x[m][k]*w[n][k] + bias[n]
// M=8192, N=4096, K=4096. Inputs arrive as int32 (one int per logical int8
// element); pack to int8 in d_ws, then run the i8 MFMA GEMM.
//
// FINAL FORM (session-best, R4/R13 = 138.9 us gemm / 49% MfmaUtil).
// Falsification matrix (14 rounds): AI 256-tile (R1 neutral), prefetch
// depth 2 (R2 neutral), 2-phase interleave (R3 +7%), 2 waves/SIMD (R4 +8%),
// barrier phasing (R5 -8%), zero-conflict LDS (R6 -26%, conflicts proven
// free), BK=128 half-sync (R7 neutral), B-direct gather (R8 -30%),
// B-pre-shuffled coalesced (R9 neutral, LDS volume exonerated), antiphase
// pairing (R10 -6%), 3 independent blocks/CU (R11 -29%, confounded),
// fine 8-phase (R12 -18%), clean independent 2-context (R14 -9%).
// The op plateaus at 42-49% MfmaUtil under every source-level structure;
// residual stall is the per-wave read-return/sync shadow.
#define M_TOT 8192
#define N_TOT 4096
#define K_TOT 4096

typedef int v4i  __attribute__((ext_vector_type(4)));
typedef int v16i __attribute__((ext_vector_type(16)));

__device__ __forceinline__ void gload_lds16(const void* g, void* l) {
    __builtin_amdgcn_global_load_lds(
        (const __attribute__((address_space(1))) unsigned int*)g,
        (__attribute__((address_space(3))) unsigned int*)l,
        16, 0, 0);
}

// gfx9 s_waitcnt simm16: vmcnt[3:0]@[3:0], expcnt@[6:4], lgkmcnt@[11:8],
// vmcnt[5:4]@[15:14].
#define WAIT_V2_L0() __builtin_amdgcn_s_waitcnt(0x0072)  // vmcnt(2) lgkmcnt(0)
#define WAIT_V0_L0() __builtin_amdgcn_s_waitcnt(0x0070)  // vmcnt(0) lgkmcnt(0)
#define WAIT_V4()    __builtin_amdgcn_s_waitcnt(0x0f74)  // vmcnt(4), lgkm free
#define SBAR()       __builtin_amdgcn_s_barrier()
#define SFENCE()     __builtin_amdgcn_sched_barrier(0)

// ---- fused pack int32 -> int8: 64B loads -> 16B store per thread-iter ----
// BW-bound at 240 MB (~45 us); split and fused variants measure the same ->
// at the traffic floor.
__global__ __launch_bounds__(256) void pack2(
        const int4* __restrict__ xs, int4* __restrict__ xd,
        const int4* __restrict__ ws, int4* __restrict__ wd) {
    const int t = blockIdx.x * 256 + threadIdx.x;       // 0..524287
#pragma unroll
    for (int it = 0; it < 6; ++it) {
        const long g = (long)it * 524288 + t;
        const int4* __restrict__ src = (it < 4) ? xs : ws;
        int4* __restrict__ dst       = (it < 4) ? xd : wd;
        const long o = (it < 4) ? g : g - 2097152;
        int4 r;
        int* rp = (int*)&r;
#pragma unroll
        for (int q = 0; q < 4; ++q) {
            const int4 a = src[o * 4 + q];
            rp[q] = (a.x & 255) | ((a.y & 255) << 8) |
                    ((a.z & 255) << 16) | (a.w << 24);
        }
        dst[o] = r;
    }
}

// ---- GEMM: 512 threads = 8 waves (2/SIMD) computing a 256x256 tile -------
// Proven cadence (R4): triple-buffered LDS, counted vmcnt, 2-phase kk split,
// ONE barrier + ONE counted wait per K-iter. 2 waves/SIMD via
// __launch_bounds__(512,2): acc = 8 v16i = 128 AGPR + ~100 VGPR fits 256.
//
// Per K-iter (per wave; tile kt in A0/B0, kt+1 in A1/B1, kt+2 -> A2/B2):
//   1) ds_read kk=1 frags of kt (6)         (hidden under step 3)
//   2) issue 2 DMAs: A-half of kt+2
//   3) MFMA kk=0 x8 (setprio)
//   4) s_waitcnt vmcnt(2) lgkmcnt(0); s_barrier
//      [drains tile kt+1's 4 DMAs, keeps kt+2's 2 in flight; retires my reads]
//   5) ds_read kk=0 frags of kt+1 (6)       (hidden under step 7)
//   6) issue 2 DMAs: B-half of kt+2
//   7) MFMA kk=1 x8 (setprio)
//   rotate buffers.
// vmcnt ledger at step 4: outstanding = kt+1's 4 (issued last iter) + kt+2's
// 2 (step 2) = 6 -> vmcnt(2) == "kt+1 landed" (in-order decrement). Tail
// iters use vmcnt(0). Buffer-reuse proof: step-2/6 DMAs target the buffer of
// tile kt-1, whose last reads (iter kt-1 step 1) were retired by iter kt-1
// step 4's lgkmcnt(0) in EVERY wave before its barrier; our issue is after.
// Reads of kt+1 at step 5 are safe: each wave's own vmcnt drain of kt+1
// precedes the same barrier. Explicit waits are REQUIRED: compiler alias
// analysis does not connect global_load_lds's LDS write to the ds_reads.
// XOR chunk swizzle: stored_chunk = logical_chunk ^ ((row>>1)&3); staging
// stays linear-in-load-order (global_load_lds needs wave-uniform LDS base).
// Residual 4-way read conflicts are hidden (R6: zero-conflict layout gained
// nothing and broke coalescing).
__global__ __launch_bounds__(512, 2) void i8gemm_bias(
        const signed char* __restrict__ x,
        const signed char* __restrict__ w,
        const int* __restrict__ bias,
        int* __restrict__ out) {
    __shared__ __align__(16) signed char la[3][256 * 64];
    __shared__ __align__(16) signed char lb[3][256 * 64];

    const int tid  = threadIdx.x;
    const int lane = tid & 63;           // 0..63
    const int wv   = tid >> 6;           // wave 0..7
    const int l31  = lane & 31;
    const int kh   = lane >> 5;          // K-half this lane supplies to MFMA
    const int wr   = wv >> 2;            // quadrant row (0..1) -> 128 rows
    const int wc   = wv & 3;             // quadrant col (0..3) -> 64 cols

    // XCD-aware bijective swizzle (512 blocks, 512%8==0): XCD k gets a
    // contiguous swz-range -> 4 A-panels x all 16 B-panels per XCD.
    const int flat = blockIdx.y * gridDim.x + blockIdx.x;   // 0..511
    const int swz  = (flat & 7) * 64 + (flat >> 3);
    const int bn0  = (swz & 15) * 256;
    const int bm0  = (swz >> 4) * 256;

    // Fused bias: C/D col = lane&31 -> bias is lane-constant per fragment.
    int bv[2];
#pragma unroll
    for (int j = 0; j < 2; ++j) bv[j] = bias[bn0 + wc * 64 + j * 32 + l31];
    v16i acc[4][2];
#pragma unroll
    for (int i = 0; i < 4; ++i)
#pragma unroll
        for (int j = 0; j < 2; ++j)
#pragma unroll
            for (int r = 0; r < 16; ++r) acc[i][j][r] = bv[j];

    // Staging: wave wv covers rows [wv*32, wv*32+32) of both A and B tiles:
    // 2 issues x (64 lanes x 16 B) each. Issue i covers rows i*16+(lane>>2);
    // stored chunk = lane&3; fetched chunk = (lane&3) ^ ((row>>1)&3)
    // = (lane&3) ^ ((lane>>3)&3).
    const int fc = (lane & 3) ^ ((lane >> 3) & 3);
    const signed char* pa = x + (long)(bm0 + wv * 32 + (lane >> 2)) * K_TOT + fc * 16;
    const signed char* pb = w + (long)(bn0 + wv * 32 + (lane >> 2)) * K_TOT + fc * 16;
    const int lbase = wv * 32 * 64;      // byte offset of this wave's rows

    // Fragment reads: A row = wr*128 + i*32 + l31, B row = wc*64 + j*32 + l31
    // -> swizzle = (l31>>1)&3 (bases are 0 mod 8). Logical chunk kk*2+kh is
    // stored at position (kk*2+kh)^swr.
    const int swr  = (l31 >> 1) & 3;
    const int aoff = (wr * 128 + l31) * 64;
    const int boff = (wc * 64  + l31) * 64;
    const int cs0  = ((kh    ) ^ swr) * 16;   // kk=0 chunk byte offset
    const int cs1  = ((2 + kh) ^ swr) * 16;   // kk=1 chunk byte offset

    // Rotating buffer pointers: A0/B0 = tile kt, A1/B1 = kt+1, A2/B2 = kt+2.
    signed char* A0 = &la[0][0]; signed char* A1 = &la[1][0]; signed char* A2 = &la[2][0];
    signed char* B0 = &lb[0][0]; signed char* B1 = &lb[1][0]; signed char* B2 = &lb[2][0];

    // Prologue: stage tile 0 then tile 1 (grouped per tile: vmcnt decrements
    // in issue order). 4 DMAs per tile per wave (2 A-rows + 2 B-rows).
#pragma unroll
    for (int i = 0; i < 2; ++i) {
        gload_lds16(pa + (long)i * 16 * K_TOT, A0 + lbase + i * 1024);
        gload_lds16(pb + (long)i * 16 * K_TOT, B0 + lbase + i * 1024);
    }
#pragma unroll
    for (int i = 0; i < 2; ++i) {
        gload_lds16(pa + 64 + (long)i * 16 * K_TOT, A1 + lbase + i * 1024);
        gload_lds16(pb + 64 + (long)i * 16 * K_TOT, B1 + lbase + i * 1024);
    }
    WAIT_V4();                 // tile 0 landed (tile 1's 4 stay in flight)
    SBAR();
    SFENCE();

    // Preload kk=0 fragments of tile 0.
    v4i a0[4], b0[2], a1[4], b1[2];
#pragma unroll
    for (int i = 0; i < 4; ++i) a0[i] = *(const v4i*)(A0 + aoff + i * 2048 + cs0);
#pragma unroll
    for (int j = 0; j < 2; ++j) b0[j] = *(const v4i*)(B0 + boff + j * 2048 + cs0);

    const int NT = K_TOT / 64;           // 64 K-tiles
    for (int kt = 0; kt < NT; ++kt) {
        SFENCE();
        // 1) ds_read kk=1 of tile kt (consumed by step 7; hidden by step 3).
#pragma unroll
        for (int i = 0; i < 4; ++i) a1[i] = *(const v4i*)(A0 + aoff + i * 2048 + cs1);
#pragma unroll
        for (int j = 0; j < 2; ++j) b1[j] = *(const v4i*)(B0 + boff + j * 2048 + cs1);
        SFENCE();
        // 2) Issue A-half prefetch of tile kt+2 (fire-and-forget).
        if (kt + 2 < NT) {
            const long k0 = (long)(kt + 2) * 64;
#pragma unroll
            for (int i = 0; i < 2; ++i)
                gload_lds16(pa + k0 + (long)i * 16 * K_TOT, A2 + lbase + i * 1024);
        }
        SFENCE();
        // 3) MFMA kk=0 (8): hides step-1 reads and step-2 issues.
        __builtin_amdgcn_s_setprio(1);
#pragma unroll
        for (int i = 0; i < 4; ++i)
#pragma unroll
            for (int j = 0; j < 2; ++j)
                acc[i][j] = __builtin_amdgcn_mfma_i32_32x32x32_i8(
                    a0[i], b0[j], acc[i][j], 0, 0, 0);
        __builtin_amdgcn_s_setprio(0);
        SFENCE();
        // 4) Publish/acquire: tile kt+1 landed everywhere, my reads retired.
        if (kt + 2 < NT) { WAIT_V2_L0(); } else { WAIT_V0_L0(); }
        SFENCE();
        SBAR();
        SFENCE();
        // 5) ds_read kk=0 of tile kt+1 (hidden by step 7).
        if (kt + 1 < NT) {
#pragma unroll
            for (int i = 0; i < 4; ++i) a0[i] = *(const v4i*)(A1 + aoff + i * 2048 + cs0);
#pragma unroll
            for (int j = 0; j < 2; ++j) b0[j] = *(const v4i*)(B1 + boff + j * 2048 + cs0);
        }
        SFENCE();
        // 6) Issue B-half prefetch of tile kt+2 (fire-and-forget).
        if (kt + 2 < NT) {
            const long k0 = (long)(kt + 2) * 64;
#pragma unroll
            for (int i = 0; i < 2; ++i)
                gload_lds16(pb + k0 + (long)i * 16 * K_TOT, B2 + lbase + i * 1024);
        }
        SFENCE();
        // 7) MFMA kk=1 (8): hides step-5 reads (a1/b1 drained at step 4).
        __builtin_amdgcn_s_setprio(1);
#pragma unroll
        for (int i = 0; i < 4; ++i)
#pragma unroll
            for (int j = 0; j < 2; ++j)
                acc[i][j] = __builtin_amdgcn_mfma_i32_32x32x32_i8(
                    a1[i], b1[j], acc[i][j], 0, 0, 0);

        // Rotate buffers (register pointer swap, no dynamic indexing).
        signed char* t;
        t = A0; A0 = A1; A1 = A2; A2 = t;
        t = B0; B0 = B1; B1 = B2; B2 = t;
    }

    // Epilogue: C/D layout col=lane&31, row=(reg&3)+8*(reg>>2)+4*(lane>>5).
#pragma unroll
    for (int i = 0; i < 4; ++i) {
        const int mbase = bm0 + wr * 128 + i * 32 + 4 * kh;
#pragma unroll
        for (int j = 0; j < 2; ++j) {
            const int n = bn0 + wc * 64 + j * 32 + l31;
#pragma unroll
            for (int r = 0; r < 16; ++r) {
                const int m = mbase + (r & 3) + 8 * (r >> 2);
                out[(long)m * N_TOT + n] = acc[i][j][r];
            }
        }
    }
}

extern "C" void kernel_launch(void* const* d_in, const int* in_sizes, int n_in,
                              void* d_out, int out_size, void* d_ws, size_t ws_size,
                              hipStream_t stream) {
    const int* x32  = (const int*)d_in[0];  // [8192,4096] logical i8 as i32
    const int* w32  = (const int*)d_in[1];  // [4096,4096] logical i8 as i32
    const int* bias = (const int*)d_in[2];  // [4096] i32
    int*       out  = (int*)d_out;          // [8192,4096] i32

    signed char* xp = (signed char*)d_ws;
    signed char* wp = (signed char*)d_ws + (size_t)M_TOT * K_TOT;

    pack2<<<2048, 256, 0, stream>>>((const int4*)x32, (int4*)xp,
                                    (const int4*)w32, (int4*)wp);

    dim3 grid(N_TOT / 256, M_TOT / 256);  // (16, 32)
    i8gemm_bias<<<grid, 512, 0, stream>>>(xp, wp, bias, out);
}